// Round 13
// baseline (253.671 us; speedup 1.0000x reference)
//
#include <hip/hip_runtime.h>
#include <math.h>
#include <limits.h>

#define TPB   1024          // 16 waves/block = 4 waves/SIMD (latency hiding)
#define TILE  1024          // sort: 1 element per thread
#define MAXT  2048
#define TPAD  64            // pad so unconditional reads past e stay in-bounds
#define MAXK  1024
#define MAXW  29            // max span width in this problem (W=30 -> w<=29)
#define BATCH 1024          // greedy candidates per round (1 per thread)
#define FLAGSTRIDE 16       // words per flag (64B line each)

// ===========================================================================
// Fused kernel: 4-pass LSD radix argsort (60 blocks) + single-block greedy.
// v13 = v12 + O(1) greedy pre-check via rejection bitmap R[start] (bit w =
//       span (s,s+w) crosses an accepted span), maintained by a BATCHED
//       parallel round-end update (item = accept x lane-offset; ~2/thread at
//       1024 threads, TLP-hidden at 4 waves/SIMD). Resolver unchanged.
// ===========================================================================
struct SortSM {
  union {
    unsigned h[4 * 256];                  // P0: 4 pass histograms
    unsigned wcnt[16][256];               // [wave][digit], scanned in place
  };
  unsigned baseL[256];
};

// Distributed full barrier: every block sets its own flag line, all blocks
// poll all nblk lines (thread t polls line t). Agent-scope load poll with a
// periodic RMW fallback guarantees progress (R6-validated coherence).
__device__ inline void dbar(unsigned* flg, int nblk) {
  __syncthreads();
  if (threadIdx.x == 0) {
    __threadfence();                       // release: this block's data
    atomicExch(&flg[blockIdx.x * FLAGSTRIDE], 1u);
  }
  if ((int)threadIdx.x < nblk) {
    int spin = 0;
    while (__hip_atomic_load(&flg[threadIdx.x * FLAGSTRIDE], __ATOMIC_ACQUIRE,
                             __HIP_MEMORY_SCOPE_AGENT) == 0u) {
      __builtin_amdgcn_s_sleep(2);
      if ((++spin & 255) == 0) {
        if (atomicAdd(&flg[threadIdx.x * FLAGSTRIDE], 0u) != 0u) break;
      }
    }
  }
  __syncthreads();
  if (threadIdx.x == 0) __threadfence();   // acquire: other blocks' data
  __syncthreads();
}

__device__ inline bool precheck30(const unsigned* tabP, int cc, int cs, int ce) {
  if (cc < 0) return false;
  int w = ce - cs;
  bool crossed = false;
  #pragma unroll
  for (int off = 0; off <= MAXW; ++off) {
    unsigned tv = tabP[cs + off];
    crossed |= ((off >= 1) & (off <= w) & ((tv & 0xFFFFu) > (unsigned)(ce + 1)))
             | ((off < w) & ((tv >> 16) < (unsigned)cs));
  }
  for (int off = MAXW + 1; off <= w; ++off) {   // generic fallback (unused)
    unsigned tv = tabP[cs + off];
    crossed |= ((tv & 0xFFFFu) > (unsigned)(ce + 1));
    if (off < w) crossed |= ((tv >> 16) < (unsigned)cs);
  }
  return !crossed;
}

__global__ void __launch_bounds__(TPB, 4) fused_kernel(
    const int* __restrict__ spans, const float* __restrict__ scores,
    const float* __restrict__ mask, const int* __restrict__ tnum_p,
    const int* __restrict__ keep_p, float* __restrict__ out, int N, int nT,
    unsigned* pflag, unsigned* ghist, unsigned* tileCnt,
    unsigned* keysA, unsigned* keysB, int* idxA, int* idxB) {
  const int2* spans2 = (const int2*)spans;
  __shared__ SortSM s;
  __shared__ unsigned base4[4][256];      // per-block copy of scanned bases
  const int tid = threadIdx.x;
  const int lane = tid & 63;
  const int wave = tid >> 6;              // 0..15

  // ======================= SORT (all blocks) ==============================
  // ---- P0: build keys + all 4 histograms in one read ----
  if (tid < 1024) s.h[tid] = 0;
  __syncthreads();
  {
    int i = blockIdx.x * TILE + tid;
    if (i < N) {
      float kf = scores[i] + logf(mask[i]);            // mask==1 -> +0 exact
      unsigned u = __float_as_uint(kf);
      u = (u & 0x80000000u) ? ~u : (u | 0x80000000u);
      u = ~u;                                          // descending order
      keysA[i] = u;
      atomicAdd(&s.h[(u & 255u)], 1u);
      atomicAdd(&s.h[256 + ((u >> 8) & 255u)], 1u);
      atomicAdd(&s.h[512 + ((u >> 16) & 255u)], 1u);
      atomicAdd(&s.h[768 + (u >> 24)], 1u);
    }
    __syncthreads();
    if (tid < 1024 && s.h[tid]) atomicAdd(&ghist[tid], s.h[tid]);
  }
  dbar(pflag + 0 * nT * FLAGSTRIDE, nT);

  // ---- digit-base exclusive scans: wave p (p<4) scans pass p via shfl ----
  if (wave < 4) {
    const int p = wave;
    unsigned v0 = ghist[p * 256 + 4 * lane + 0];
    unsigned v1 = ghist[p * 256 + 4 * lane + 1];
    unsigned v2 = ghist[p * 256 + 4 * lane + 2];
    unsigned v3 = ghist[p * 256 + 4 * lane + 3];
    unsigned sum = v0 + v1 + v2 + v3;
    unsigned x = sum;
    for (int off = 1; off < 64; off <<= 1) {
      unsigned y = __shfl_up(x, off, 64);
      if (lane >= off) x += y;
    }
    unsigned excl = x - sum;               // exclusive over 4-bin chunks
    base4[p][4 * lane + 0] = excl;
    base4[p][4 * lane + 1] = excl + v0;
    base4[p][4 * lane + 2] = excl + v0 + v1;
    base4[p][4 * lane + 3] = excl + v0 + v1 + v2;
  }
  __syncthreads();

  // ---- 4 fused rank/scatter radix passes (1 element per thread) ----
  for (int p = 0; p < 4; ++p) {
    const unsigned* srck = (p & 1) ? keysB : keysA;
    const int*      srci = (p & 1) ? idxB : idxA;     // p==0: payload = i
    unsigned*       dstk = (p & 1) ? keysA : keysB;
    int*            dsti = (p & 1) ? idxA : idxB;
    const int shift = 8 * p;
    unsigned* lbf = pflag + (1 + p) * nT * FLAGSTRIDE;

    for (int j = tid; j < 16 * 256; j += TPB)
      (&s.wcnt[0][0])[j] = 0;
    __syncthreads();

    int i = blockIdx.x * TILE + tid;
    bool v = (i < N);
    unsigned key = v ? srck[i] : 0u;
    int pay = v ? ((p == 0) ? i : srci[i]) : 0;
    unsigned d = (key >> shift) & 255u;
    unsigned long long mm = __ballot(v);     // stable rank within wave
    #pragma unroll
    for (int b = 0; b < 8; ++b) {
      unsigned long long bb = __ballot((d >> b) & 1u);
      mm &= ((d >> b) & 1u) ? bb : ~bb;
    }
    unsigned rnk = (unsigned)__popcll(mm & ((1ull << lane) - 1ull));
    if (v && rnk == 0) s.wcnt[wave][d] = (unsigned)__popcll(mm);
    __syncthreads();
    if (tid < 256) {                       // one 16-way scan per digit
      unsigned run = 0;
      #pragma unroll
      for (int g = 0; g < 16; ++g) {
        unsigned c = s.wcnt[g][tid];
        s.wcnt[g][tid] = run;
        run += c;
      }
      tileCnt[blockIdx.x * 256 + tid] = run;
    }
    __syncthreads();                       // all tileCnt writes issued

    // ---- publish + decoupled lookback (block b needs only t<b) ----
    if (tid == 0) {
      __threadfence();                     // release: tileCnt visible
      atomicExch(&lbf[blockIdx.x * FLAGSTRIDE], 1u);
    }
    if (tid < blockIdx.x) {                // one thread polls one predecessor
      int spin = 0;
      while (__hip_atomic_load(&lbf[tid * FLAGSTRIDE], __ATOMIC_ACQUIRE,
                               __HIP_MEMORY_SCOPE_AGENT) == 0u) {
        __builtin_amdgcn_s_sleep(2);
        if ((++spin & 255) == 0) {
          if (atomicAdd(&lbf[tid * FLAGSTRIDE], 0u) != 0u) break;
        }
      }
    }
    __syncthreads();
    if (tid == 0) __threadfence();         // acquire
    __syncthreads();

    if (tid < 256) {
      unsigned baseacc = base4[p][tid];
      for (int t = 0; t < blockIdx.x; ++t)
        baseacc += tileCnt[t * 256 + tid];
      s.baseL[tid] = baseacc;
    }
    __syncthreads();
    if (v) {
      unsigned pos = s.baseL[d] + s.wcnt[wave][d] + rnk;
      dstk[pos] = key;
      dsti[pos] = pay;
    }
    if (p < 3) {
      dbar(pflag + (5 + p) * nT * FLAGSTRIDE, nT);   // scatter-complete
    }
  }

  // ---- final scatter published; non-zero blocks exit ----
  {
    unsigned* fin = pflag + 8 * nT * FLAGSTRIDE;
    __syncthreads();
    if (tid == 0) {
      __threadfence();
      atomicExch(&fin[blockIdx.x * FLAGSTRIDE], 1u);
    }
    if (blockIdx.x != 0) return;
    if (tid < nT) {                        // block 0 waits for all scatters
      int spin = 0;
      while (__hip_atomic_load(&fin[tid * FLAGSTRIDE], __ATOMIC_ACQUIRE,
                               __HIP_MEMORY_SCOPE_AGENT) == 0u) {
        __builtin_amdgcn_s_sleep(2);
        if ((++spin & 255) == 0) {
          if (atomicAdd(&fin[tid * FLAGSTRIDE], 0u) != 0u) break;
        }
      }
    }
    __syncthreads();
    if (tid == 0) __threadfence();
    __syncthreads();
  }

  // ======================= GREEDY (block 0 only) ==========================
  const int* order = idxA;                 // final order (A->B->A->B->A)
  __shared__ unsigned tabP[MAXT + TPAD];   // hi16 = e2s(enc), lo16 = s2e+1
  __shared__ int2 tab[MAXT + TPAD];        // authoritative: .x=s2e, .y=e2s
  __shared__ unsigned R[MAXT];             // rejection bitmap (round-fresh)
  __shared__ unsigned long long acc[MAXK];
  __shared__ unsigned racc_s[MAXK];        // accepted (s<<16|e), for R update
  __shared__ unsigned long long surv[BATCH];
  __shared__ unsigned long long Cmat[BATCH];   // in-group crossing rows
  __shared__ int wvs[16];                      // survivor count per wave
  __shared__ int gcnt;

  const int T  = tnum_p[0];
  const int k0 = keep_p[0];
  const int k  = (k0 < MAXK) ? k0 : MAXK;

  for (int t = tid; t < MAXT + TPAD; t += TPB) {
    tab[t] = make_int2(-1, INT_MAX);
    tabP[t] = 0xFFFF0000u;               // s2e+1 = 0, e2s_enc = 0xFFFF
    if (t < MAXT) R[t] = 0u;
  }
  if (tid == 0) gcnt = 0;
  __syncthreads();

  // Each thread owns candidate c0+tid of every round. ids prefetched 2
  // rounds ahead, spans 1 round ahead.
  int cc = -1, cs = 0, ce = 0, nn = -1;
  if (tid < N)         cc = order[tid];
  if (BATCH + tid < N) nn = order[BATCH + tid];
  if (cc >= 0) { int2 sp = spans2[cc]; cs = sp.x; ce = sp.y; }

  int cnt = 0;
  for (int c0 = 0; c0 < N && cnt < k; c0 += BATCH) {
    // ---- prefetch next-round span + next-next-round id ----
    int pc = nn, ps = 0, pe = 0;
    if (pc >= 0) { int2 sp = spans2[pc]; ps = sp.x; pe = sp.y; }
    int i2 = c0 + 2 * BATCH + tid;
    nn = (i2 < N) ? order[i2] : -1;

    // ---- O(1) pre-check: 1 LDS read (R fresh as of end of last round) ----
    bool ok = (cc >= 0) && !((R[cs] >> (unsigned)(ce - cs)) & 1u);
    unsigned long long bal = __ballot(ok);
    if (lane == 0) wvs[wave] = (int)__popcll(bal);
    __syncthreads();
    int ns = 0, wb = 0;
    #pragma unroll
    for (int w2 = 0; w2 < 16; ++w2) {
      if (w2 == wave) wb = ns;
      ns += wvs[w2];
    }

    if (ns > 0) {              // uniform branch: all threads agree on ns
      // ---- order-preserving survivor compression -> LDS ----
      if (ok) {
        int pos = wb + (int)__popcll(bal & ((1ull << lane) - 1ull));
        surv[pos] = ((unsigned long long)(unsigned)cs << 48)
                  | ((unsigned long long)(unsigned)ce << 32)
                  | (unsigned)cc;
      }
      __syncthreads();

      // ---- parallel in-group crossing-matrix precompute ----
      for (int v = tid; v < ns; v += TPB) {
        unsigned long long pk = surv[v];
        int gs = (int)(pk >> 48), ge = (int)((pk >> 32) & 0xFFFFu);
        int gbase = v & ~63;
        int m = ns - gbase; if (m > 64) m = 64;
        unsigned long long C = 0;
        for (int j = 0; j < m; ++j) {
          unsigned long long pj = surv[gbase + j];
          int sj = (int)(pj >> 48), ej = (int)((pj >> 32) & 0xFFFFu);
          bool cr = (gs < sj && sj <= ge && ej > ge) ||
                    (sj < gs && gs <= ej && ej < ge);
          C |= (unsigned long long)cr << j;
        }
        Cmat[v] = C;
      }
      __syncthreads();

      const int cntPrev = cnt;
      // ---- wave-0 resolution, 64 survivors at a time ----
      if (tid < 64) {
        bool dirty = false;    // any in-batch acceptance since pre-check?
        for (int g = 0; g < ns && cnt < k; g += 64) {
          int m = ns - g; if (m > 64) m = 64;
          bool act = lane < m;
          int gs = 0, ge = 0, gc = 0;
          unsigned long long C = 0;
          if (act) {
            unsigned long long pk = surv[g + lane];
            gs = (int)(pk >> 48);
            ge = (int)((pk >> 32) & 0xFFFFu);
            gc = (int)(unsigned)pk;
            C  = Cmat[g + lane];
          }
          bool pre = act;
          if (dirty) {         // re-check only when tables changed in-batch
            pre = act && precheck30(tabP, gc, gs, ge);
          }
          unsigned long long preB = __ballot(pre);
          if (preB == 0ull) continue;
          int np = (int)__popcll(preB);
          unsigned long long lower = (1ull << lane) - 1ull;
          unsigned long long accm;
          int cnt0g = cnt;
          if (np == 1) {                       // single-survivor fast path
            accm = preB;
            cnt += 1;
          } else {
            // ---- parallel fixpoint: resolve ready lanes each iteration ----
            unsigned long long Cl = C & lower;        // my earlier crossers
            unsigned long long resolvedB = ~preB;     // non-pre start rejected
            accm = 0ull;
            while (true) {
              bool meUn   = ((resolvedB >> lane) & 1ull) == 0ull;
              bool killed = (Cl & accm) != 0ull;
              bool ready  = (Cl & ~resolvedB) == 0ull;
              unsigned long long newacc = __ballot(meUn && ready && !killed);
              unsigned long long newrej = __ballot(meUn && killed);
              if (!(newacc | newrej)) break;
              accm |= newacc;
              resolvedB |= (newacc | newrej);
            }
            int nacc = (int)__popcll(accm);
            if (cnt + nacc > k) {              // k-cap: keep first (k-cnt)
              int room = k - cnt;
              bool a0 = ((accm >> lane) & 1ull) != 0ull;
              int ar = (int)__popcll(accm & lower);
              accm = __ballot(a0 && (ar < room));
              nacc = room;
            }
            cnt += nacc;
          }
          bool accme = ((accm >> lane) & 1ull) != 0ull;
          if (accme) {
            int rank = (int)__popcll(accm & lower);
            acc[cnt0g + rank] =
                ((unsigned long long)(unsigned)(gs * T + ge) << 32) | (unsigned)gc;
            racc_s[cnt0g + rank] = ((unsigned)gs << 16) | (unsigned)ge;
            atomicMax(&tab[gs].x, ge);
            atomicMin(&tab[ge].y, gs);
          }
          if (accme) {      // same-wave DS in-order: reads see all atomics
            int2 tv = tab[gs];
            tabP[gs] = ((unsigned)(tv.y > 65535 ? 65535 : tv.y) << 16)
                     | (unsigned)(tv.x + 1);
            int2 tv2 = tab[ge];
            tabP[ge] = ((unsigned)(tv2.y > 65535 ? 65535 : tv2.y) << 16)
                     | (unsigned)(tv2.x + 1);
          }
          if (accm) dirty = true;
        }
        if (lane == 0) gcnt = cnt;
      }
      __syncthreads();
      cnt = gcnt;

      // ---- BATCHED parallel R update: item = (accept, lane-offset) ----
      // accepted (as,ae), ae>as, rejects:
      //   s in [as-29, as-1]: w in [as-s, min(ae-1-s, 29)]
      //   s in [as+1,  ae  ]: w in [ae-s+1, min(T-1-s, 29)]
      {
        int nacc = cnt - cntPrev;
        for (int it = tid; it < nacc * 64; it += TPB) {
          unsigned pr = racc_s[cntPrev + (it >> 6)];
          int as = (int)(pr >> 16), ae = (int)(pr & 0xFFFFu);
          if (ae > as) {
            int sx = as - MAXW + (it & 63);
            if (sx >= 0 && sx <= ae && sx != as) {
              unsigned mmask = 0u;
              if (sx < as) {
                int l1 = as - sx;
                int h1 = ae - 1 - sx; if (h1 > MAXW) h1 = MAXW;
                if (h1 >= l1)
                  mmask = ((1u << (h1 + 1)) - 1u) & ~((1u << l1) - 1u);
              } else {
                int l2 = ae - sx + 1;
                int h2 = T - 1 - sx; if (h2 > MAXW) h2 = MAXW;
                if (h2 >= l2)
                  mmask = ((1u << (h2 + 1)) - 1u) & ~((1u << l2) - 1u);
              }
              if (mmask) atomicOr(&R[sx], mmask);
            }
          }
        }
      }
      __syncthreads();   // next round's pre-check reads R
    }

    cc = pc; cs = ps; ce = pe;
  }

  // ---- bitonic ascending sort of acc[0..cnt) by (s*T+e, cand) ----
  int M = 2;
  while (M < cnt) M <<= 1;
  for (int j = tid; j < M; j += TPB)
    if (j >= cnt) acc[j] = ~0ull;
  __syncthreads();
  for (int kk = 2; kk <= M; kk <<= 1) {
    for (int jj = kk >> 1; jj > 0; jj >>= 1) {
      for (int i3 = tid; i3 < M; i3 += TPB) {
        int ixj = i3 ^ jj;
        if (ixj > i3) {
          unsigned long long a = acc[i3], b = acc[ixj];
          bool up = ((i3 & kk) == 0);
          if ((a > b) == up) { acc[i3] = b; acc[ixj] = a; }
        }
      }
      __syncthreads();
    }
  }

  // ---- epilogue: scores | idx | spans | valid, all f32 ----
  for (int j = tid; j < k0; j += TPB) {
    if (j < cnt) {
      int cand = (int)(acc[j] & 0xFFFFFFFFu);
      out[j]                  = scores[cand];
      out[k0 + j]             = (float)cand;
      out[2 * k0 + 2 * j]     = (float)spans[2 * cand];
      out[2 * k0 + 2 * j + 1] = (float)spans[2 * cand + 1];
      out[4 * k0 + j]         = 1.0f;
    } else {
      out[j]                  = 0.0f;
      out[k0 + j]             = 0.0f;
      out[2 * k0 + 2 * j]     = 0.0f;
      out[2 * k0 + 2 * j + 1] = 0.0f;
      out[4 * k0 + j]         = 0.0f;
    }
  }
}

extern "C" void kernel_launch(void* const* d_in, const int* in_sizes, int n_in,
                              void* d_out, int out_size, void* d_ws, size_t ws_size,
                              hipStream_t stream) {
  const int*   spans  = (const int*)d_in[0];
  const float* scores = (const float*)d_in[1];
  const float* mask   = (const float*)d_in[2];
  const int*   tnum   = (const int*)d_in[3];
  const int*   keep   = (const int*)d_in[4];
  const int N = in_sizes[1];
  const int nT = (N + TILE - 1) / TILE;   // 60 for N=61440

  // ws: pflag[9*nT*FS] | ghist[1024] | tileCnt[nT*256] | keysA/B | idxA/B
  unsigned* pflag   = (unsigned*)d_ws;
  unsigned* ghist   = pflag + (size_t)9 * nT * FLAGSTRIDE;
  unsigned* tileCnt = ghist + 1024;
  unsigned* keysA   = tileCnt + (size_t)nT * 256;
  unsigned* keysB   = keysA + N;
  int*      idxA    = (int*)(keysB + N);
  int*      idxB    = idxA + N;
  float*    out     = (float*)d_out;

  hipMemsetAsync(pflag, 0,
                 ((size_t)9 * nT * FLAGSTRIDE + 1024) * sizeof(unsigned),
                 stream);

  fused_kernel<<<nT, TPB, 0, stream>>>(spans, scores, mask, tnum, keep, out,
                                       N, nT, pflag, ghist, tileCnt,
                                       keysA, keysB, idxA, idxB);
}

// Round 14
// 227.697 us; speedup vs baseline: 1.1141x; 1.1141x over previous
//
#include <hip/hip_runtime.h>
#include <math.h>
#include <limits.h>

#define TPB   1024          // 16 waves/block = 4 waves/SIMD (latency hiding)
#define TILE  1024          // sort: 1 element per thread
#define MAXT  2048
#define TPAD  64            // pad so unconditional reads past e stay in-bounds
#define MAXK  1024
#define MAXW  29            // max span width in this problem (W=30 -> w<=29)
#define BATCH 1024          // greedy candidates per round (1 per thread)
#define FLAGSTRIDE 16       // words per lookback flag (64B line each)

// ===========================================================================
// Kernel A: fused key-build + 4-pass LSD radix argsort (60 blocks x 1024 thr)
// v14 = v11 + 4-way chunked baseL accumulation (breaks block-59's ~59-load
//       serial chain on the pass critical path).
// ===========================================================================
struct SortSM {
  union {
    unsigned h[4 * 256];                  // P0: 4 pass histograms
    unsigned wcnt[16][256];               // [wave][digit], scanned in place
  };
  unsigned baseL[256];
  unsigned part[4][256];                  // chunked tileCnt partial sums
};

// Device-scope grid barrier. SAFE: grid (60 blocks, 16 waves each) fully
// co-resident on 256 CUs. ctr[] zeroed by memset node each launch.
__device__ inline void gbar(unsigned* ctr, int idx, unsigned nblk) {
  __syncthreads();
  if (threadIdx.x == 0) {
    __threadfence();
    atomicAdd(&ctr[idx], 1u);
    while (atomicAdd(&ctr[idx], 0u) < nblk) { __builtin_amdgcn_s_sleep(8); }
    __threadfence();
  }
  __syncthreads();
}

__global__ void __launch_bounds__(TPB, 4) sort_kernel(
    const float* __restrict__ scores, const float* __restrict__ mask,
    int N, int nT, unsigned* ctr, unsigned* pflag, unsigned* ghist,
    unsigned* tileCnt, unsigned* keysA, unsigned* keysB, int* idxA, int* idxB) {
  __shared__ SortSM s;
  __shared__ unsigned base4[4][256];      // per-block copy of scanned bases
  const int tid = threadIdx.x;
  const int lane = tid & 63;
  const int wave = tid >> 6;              // 0..15

  // ---- P0: build keys + all 4 histograms in one read ----
  if (tid < 1024) s.h[tid] = 0;
  __syncthreads();
  {
    int i = blockIdx.x * TILE + tid;
    if (i < N) {
      float kf = scores[i] + logf(mask[i]);            // mask==1 -> +0 exact
      unsigned u = __float_as_uint(kf);
      u = (u & 0x80000000u) ? ~u : (u | 0x80000000u);
      u = ~u;                                          // descending order
      keysA[i] = u;
      atomicAdd(&s.h[(u & 255u)], 1u);
      atomicAdd(&s.h[256 + ((u >> 8) & 255u)], 1u);
      atomicAdd(&s.h[512 + ((u >> 16) & 255u)], 1u);
      atomicAdd(&s.h[768 + (u >> 24)], 1u);
    }
    __syncthreads();
    if (tid < 1024 && s.h[tid]) atomicAdd(&ghist[tid], s.h[tid]);
  }
  gbar(ctr, 0, nT);

  // ---- digit-base exclusive scans: wave p (p<4) scans pass p via shfl ----
  if (wave < 4) {
    const int p = wave;
    unsigned v0 = ghist[p * 256 + 4 * lane + 0];
    unsigned v1 = ghist[p * 256 + 4 * lane + 1];
    unsigned v2 = ghist[p * 256 + 4 * lane + 2];
    unsigned v3 = ghist[p * 256 + 4 * lane + 3];
    unsigned sum = v0 + v1 + v2 + v3;
    unsigned x = sum;
    for (int off = 1; off < 64; off <<= 1) {
      unsigned y = __shfl_up(x, off, 64);
      if (lane >= off) x += y;
    }
    unsigned excl = x - sum;               // exclusive over 4-bin chunks
    base4[p][4 * lane + 0] = excl;
    base4[p][4 * lane + 1] = excl + v0;
    base4[p][4 * lane + 2] = excl + v0 + v1;
    base4[p][4 * lane + 3] = excl + v0 + v1 + v2;
  }
  __syncthreads();

  // ---- 4 fused rank/scatter radix passes (1 element per thread) ----
  for (int p = 0; p < 4; ++p) {
    const unsigned* srck = (p & 1) ? keysB : keysA;
    const int*      srci = (p & 1) ? idxB : idxA;     // p==0: payload = i
    unsigned*       dstk = (p & 1) ? keysA : keysB;
    int*            dsti = (p & 1) ? idxA : idxB;
    const int shift = 8 * p;
    unsigned* flg = pflag + p * nT * FLAGSTRIDE;

    for (int j = tid; j < 16 * 256; j += TPB)
      (&s.wcnt[0][0])[j] = 0;
    __syncthreads();

    int i = blockIdx.x * TILE + tid;
    bool v = (i < N);
    unsigned key = v ? srck[i] : 0u;
    int pay = v ? ((p == 0) ? i : srci[i]) : 0;
    unsigned d = (key >> shift) & 255u;
    unsigned long long mm = __ballot(v);     // stable rank within wave
    #pragma unroll
    for (int b = 0; b < 8; ++b) {
      unsigned long long bb = __ballot((d >> b) & 1u);
      mm &= ((d >> b) & 1u) ? bb : ~bb;
    }
    unsigned rnk = (unsigned)__popcll(mm & ((1ull << lane) - 1ull));
    if (v && rnk == 0) s.wcnt[wave][d] = (unsigned)__popcll(mm);
    __syncthreads();
    if (tid < 256) {                       // one 16-way scan per digit
      unsigned run = 0;
      #pragma unroll
      for (int g = 0; g < 16; ++g) {
        unsigned c = s.wcnt[g][tid];
        s.wcnt[g][tid] = run;
        run += c;
      }
      tileCnt[blockIdx.x * 256 + tid] = run;
    }
    __syncthreads();                       // all tileCnt writes issued

    // ---- publish + decoupled lookback (replaces full grid barrier) ----
    if (tid == 0) {
      __threadfence();                     // release: tileCnt visible
      atomicExch(&flg[blockIdx.x * FLAGSTRIDE], 1u);
    }
    if (tid < blockIdx.x) {                // one thread polls one predecessor
      while (atomicAdd(&flg[tid * FLAGSTRIDE], 0u) == 0u)
        __builtin_amdgcn_s_sleep(2);
    }
    __syncthreads();
    if (tid == 0) __threadfence();         // acquire: invalidate stale lines
    __syncthreads();

    // ---- 4-way chunked prefix accumulation (v14): thread = (chunk,digit) --
    {
      int digit = tid & 255;
      int chunk = tid >> 8;                // 0..3
      int b = blockIdx.x;
      int Q = (b + 3) >> 2;                // ceil(b/4)
      int t0 = chunk * Q;
      int t1 = t0 + Q; if (t1 > b) t1 = b;
      unsigned acc2 = 0;
      for (int t = t0; t < t1; ++t)
        acc2 += tileCnt[t * 256 + digit];
      s.part[chunk][digit] = acc2;
    }
    __syncthreads();
    if (tid < 256) {
      s.baseL[tid] = base4[p][tid] + s.part[0][tid] + s.part[1][tid]
                   + s.part[2][tid] + s.part[3][tid];
    }
    __syncthreads();
    if (v) {
      unsigned pos = s.baseL[d] + s.wcnt[wave][d] + rnk;
      dstk[pos] = key;
      dsti[pos] = pay;
    }
    if (p < 3) gbar(ctr, 1 + p, nT);       // scatter-complete: full barrier
  }
  // final order in idxA (A->B->A->B->A)
}

// ===========================================================================
// Kernel B: batched-speculative greedy (1 block, 1024 threads) + epilogue.
// v10/v11 (unchanged, best-measured 110 us): 1 candidate/thread, wave-0
// resolution with parallel fixpoint, tabP dirty-recheck. 16 waves = 4/SIMD.
// ===========================================================================
__device__ inline bool precheck30(const unsigned* tabP, int cc, int cs, int ce) {
  if (cc < 0) return false;
  int w = ce - cs;
  bool crossed = false;
  #pragma unroll
  for (int off = 0; off <= MAXW; ++off) {
    unsigned tv = tabP[cs + off];
    crossed |= ((off >= 1) & (off <= w) & ((tv & 0xFFFFu) > (unsigned)(ce + 1)))
             | ((off < w) & ((tv >> 16) < (unsigned)cs));
  }
  for (int off = MAXW + 1; off <= w; ++off) {   // generic fallback (unused)
    unsigned tv = tabP[cs + off];
    crossed |= ((tv & 0xFFFFu) > (unsigned)(ce + 1));
    if (off < w) crossed |= ((tv >> 16) < (unsigned)cs);
  }
  return !crossed;
}

__global__ void __launch_bounds__(TPB, 4) greedy_kernel(
    const int2* __restrict__ spans2, const int* __restrict__ spans,
    const float* __restrict__ scores, const int* __restrict__ order,
    const int* __restrict__ tnum_p, const int* __restrict__ keep_p,
    float* __restrict__ out, int N) {
  __shared__ unsigned tabP[MAXT + TPAD];  // hi16 = e2s(enc), lo16 = s2e+1
  __shared__ int2 tab[MAXT + TPAD];       // authoritative: .x=s2e, .y=e2s
  __shared__ unsigned long long acc[MAXK];
  __shared__ unsigned long long surv[BATCH];
  __shared__ unsigned long long Cmat[BATCH];   // in-group crossing rows
  __shared__ int wvs[16];                      // survivor count per wave
  __shared__ int gcnt;

  const int tid = threadIdx.x;
  const int lane = tid & 63;
  const int wave = tid >> 6;              // 0..15
  const int T  = tnum_p[0];
  const int k0 = keep_p[0];
  const int k  = (k0 < MAXK) ? k0 : MAXK;

  for (int t = tid; t < MAXT + TPAD; t += TPB) {
    tab[t] = make_int2(-1, INT_MAX);
    tabP[t] = 0xFFFF0000u;               // s2e+1 = 0, e2s_enc = 0xFFFF
  }
  if (tid == 0) gcnt = 0;
  __syncthreads();

  // Each thread owns candidate c0+tid of every round. ids prefetched 2
  // rounds ahead, spans 1 round ahead.
  int cc = -1, cs = 0, ce = 0, nn = -1;
  if (tid < N)         cc = order[tid];
  if (BATCH + tid < N) nn = order[BATCH + tid];
  if (cc >= 0) { int2 sp = spans2[cc]; cs = sp.x; ce = sp.y; }

  int cnt = 0;
  for (int c0 = 0; c0 < N && cnt < k; c0 += BATCH) {
    // ---- prefetch next-round span + next-next-round id ----
    int pc = nn, ps = 0, pe = 0;
    if (pc >= 0) { int2 sp = spans2[pc]; ps = sp.x; pe = sp.y; }
    int i2 = c0 + 2 * BATCH + tid;
    nn = (i2 < N) ? order[i2] : -1;

    // ---- parallel pre-check vs packed tables (monotone -> speculative) ----
    bool ok = precheck30(tabP, cc, cs, ce);
    unsigned long long bal = __ballot(ok);
    if (lane == 0) wvs[wave] = (int)__popcll(bal);
    __syncthreads();
    int ns = 0, wb = 0;
    #pragma unroll
    for (int w2 = 0; w2 < 16; ++w2) {
      if (w2 == wave) wb = ns;
      ns += wvs[w2];
    }

    if (ns > 0) {              // uniform branch: all threads agree on ns
      // ---- order-preserving survivor compression -> LDS ----
      if (ok) {
        int pos = wb + (int)__popcll(bal & ((1ull << lane) - 1ull));
        surv[pos] = ((unsigned long long)(unsigned)cs << 48)
                  | ((unsigned long long)(unsigned)ce << 32)
                  | (unsigned)cc;
      }
      __syncthreads();

      // ---- parallel in-group crossing-matrix precompute ----
      for (int v = tid; v < ns; v += TPB) {
        unsigned long long pk = surv[v];
        int gs = (int)(pk >> 48), ge = (int)((pk >> 32) & 0xFFFFu);
        int gbase = v & ~63;
        int m = ns - gbase; if (m > 64) m = 64;
        unsigned long long C = 0;
        for (int j = 0; j < m; ++j) {
          unsigned long long pj = surv[gbase + j];
          int sj = (int)(pj >> 48), ej = (int)((pj >> 32) & 0xFFFFu);
          bool cr = (gs < sj && sj <= ge && ej > ge) ||
                    (sj < gs && gs <= ej && ej < ge);
          C |= (unsigned long long)cr << j;
        }
        Cmat[v] = C;
      }
      __syncthreads();

      // ---- wave-0 resolution, 64 survivors at a time ----
      if (tid < 64) {
        bool dirty = false;    // any in-batch acceptance since pre-check?
        for (int g = 0; g < ns && cnt < k; g += 64) {
          int m = ns - g; if (m > 64) m = 64;
          bool act = lane < m;
          int gs = 0, ge = 0, gc = 0;
          unsigned long long C = 0;
          if (act) {
            unsigned long long pk = surv[g + lane];
            gs = (int)(pk >> 48);
            ge = (int)((pk >> 32) & 0xFFFFu);
            gc = (int)(unsigned)pk;
            C  = Cmat[g + lane];
          }
          bool pre = act;
          if (dirty) {         // re-check only when tables changed in-batch
            pre = act && precheck30(tabP, gc, gs, ge);
          }
          unsigned long long preB = __ballot(pre);
          if (preB == 0ull) continue;
          int np = (int)__popcll(preB);
          unsigned long long lower = (1ull << lane) - 1ull;
          unsigned long long accm;
          int cnt0g = cnt;
          if (np == 1) {                       // single-survivor fast path
            accm = preB;
            cnt += 1;
          } else {
            // ---- parallel fixpoint: resolve ready lanes each iteration ----
            unsigned long long Cl = C & lower;        // my earlier crossers
            unsigned long long resolvedB = ~preB;     // non-pre start rejected
            accm = 0ull;
            while (true) {
              bool meUn   = ((resolvedB >> lane) & 1ull) == 0ull;
              bool killed = (Cl & accm) != 0ull;
              bool ready  = (Cl & ~resolvedB) == 0ull;
              unsigned long long newacc = __ballot(meUn && ready && !killed);
              unsigned long long newrej = __ballot(meUn && killed);
              if (!(newacc | newrej)) break;
              accm |= newacc;
              resolvedB |= (newacc | newrej);
            }
            int nacc = (int)__popcll(accm);
            if (cnt + nacc > k) {              // k-cap: keep first (k-cnt)
              int room = k - cnt;
              bool a0 = ((accm >> lane) & 1ull) != 0ull;
              int ar = (int)__popcll(accm & lower);
              accm = __ballot(a0 && (ar < room));
              nacc = room;
            }
            cnt += nacc;
          }
          bool accme = ((accm >> lane) & 1ull) != 0ull;
          if (accme) {
            int rank = (int)__popcll(accm & lower);
            acc[cnt0g + rank] =
                ((unsigned long long)(unsigned)(gs * T + ge) << 32) | (unsigned)gc;
            atomicMax(&tab[gs].x, ge);
            atomicMin(&tab[ge].y, gs);
          }
          if (accme) {      // same-wave DS in-order: reads see all atomics
            int2 tv = tab[gs];
            tabP[gs] = ((unsigned)(tv.y > 65535 ? 65535 : tv.y) << 16)
                     | (unsigned)(tv.x + 1);
            int2 tv2 = tab[ge];
            tabP[ge] = ((unsigned)(tv2.y > 65535 ? 65535 : tv2.y) << 16)
                     | (unsigned)(tv2.x + 1);
          }
          if (accm) dirty = true;
        }
        if (lane == 0) gcnt = cnt;
      }
      __syncthreads();
      cnt = gcnt;
    }

    cc = pc; cs = ps; ce = pe;
  }

  // ---- bitonic ascending sort of acc[0..cnt) by (s*T+e, cand) ----
  int M = 2;
  while (M < cnt) M <<= 1;
  for (int j = tid; j < M; j += TPB)
    if (j >= cnt) acc[j] = ~0ull;
  __syncthreads();
  for (int kk = 2; kk <= M; kk <<= 1) {
    for (int jj = kk >> 1; jj > 0; jj >>= 1) {
      for (int i3 = tid; i3 < M; i3 += TPB) {
        int ixj = i3 ^ jj;
        if (ixj > i3) {
          unsigned long long a = acc[i3], b = acc[ixj];
          bool up = ((i3 & kk) == 0);
          if ((a > b) == up) { acc[i3] = b; acc[ixj] = a; }
        }
      }
      __syncthreads();
    }
  }

  // ---- epilogue: scores | idx | spans | valid, all f32 ----
  for (int j = tid; j < k0; j += TPB) {
    if (j < cnt) {
      int cand = (int)(acc[j] & 0xFFFFFFFFu);
      out[j]                  = scores[cand];
      out[k0 + j]             = (float)cand;
      out[2 * k0 + 2 * j]     = (float)spans[2 * cand];
      out[2 * k0 + 2 * j + 1] = (float)spans[2 * cand + 1];
      out[4 * k0 + j]         = 1.0f;
    } else {
      out[j]                  = 0.0f;
      out[k0 + j]             = 0.0f;
      out[2 * k0 + 2 * j]     = 0.0f;
      out[2 * k0 + 2 * j + 1] = 0.0f;
      out[4 * k0 + j]         = 0.0f;
    }
  }
}

extern "C" void kernel_launch(void* const* d_in, const int* in_sizes, int n_in,
                              void* d_out, int out_size, void* d_ws, size_t ws_size,
                              hipStream_t stream) {
  const int*   spans  = (const int*)d_in[0];
  const float* scores = (const float*)d_in[1];
  const float* mask   = (const float*)d_in[2];
  const int*   tnum   = (const int*)d_in[3];
  const int*   keep   = (const int*)d_in[4];
  const int N = in_sizes[1];
  const int nT = (N + TILE - 1) / TILE;   // 60 for N=61440

  // ws: ctr[32] | pflag[4*nT*FS] | ghist[1024] | tileCnt[nT*256] | keysA/B | idxA/B
  unsigned* ctr     = (unsigned*)d_ws;
  unsigned* pflag   = ctr + 32;
  unsigned* ghist   = pflag + (size_t)4 * nT * FLAGSTRIDE;
  unsigned* tileCnt = ghist + 1024;
  unsigned* keysA   = tileCnt + (size_t)nT * 256;
  unsigned* keysB   = keysA + N;
  int*      idxA    = (int*)(keysB + N);
  int*      idxB    = idxA + N;
  float*    out     = (float*)d_out;

  hipMemsetAsync(ctr, 0,
                 (32 + (size_t)4 * nT * FLAGSTRIDE + 1024) * sizeof(unsigned),
                 stream);

  sort_kernel<<<nT, TPB, 0, stream>>>(scores, mask, N, nT, ctr, pflag, ghist,
                                      tileCnt, keysA, keysB, idxA, idxB);
  greedy_kernel<<<1, TPB, 0, stream>>>((const int2*)spans, spans, scores,
                                       idxA, tnum, keep, out, N);
}

// Round 15
// 227.650 us; speedup vs baseline: 1.1143x; 1.0002x over previous
//
#include <hip/hip_runtime.h>
#include <math.h>
#include <limits.h>

#define TPB   1024          // 16 waves/block = 4 waves/SIMD (latency hiding)
#define TILE  1024          // sort: 1 element per thread
#define MAXT  2048
#define TPAD  64            // pad so unconditional reads past e stay in-bounds
#define MAXK  1024
#define MAXW  29            // max span width in this problem (W=30 -> w<=29)
#define BATCH 1024          // greedy candidates per round (1 per thread)
#define FLAGSTRIDE 16       // words per flag (64B line each)

// ===========================================================================
// Kernel A: fused key-build + 4-pass LSD radix argsort (60 blocks x 1024 thr)
// v15 = v14 with the 4 remaining single-line RMW grid barriers replaced by
//       DISTRIBUTED-FLAG barriers (parallel arrival on 60 independent lines,
//       60-thread load-polling w/ RMW fallback — v12/v13-validated).
// pflag phases: p (0..3) = lookback pass p; 4 = hist barrier; 5+p = scatter.
// ===========================================================================
struct SortSM {
  union {
    unsigned h[4 * 256];                  // P0: 4 pass histograms
    unsigned wcnt[16][256];               // [wave][digit], scanned in place
  };
  unsigned baseL[256];
  unsigned part[4][256];                  // chunked tileCnt partial sums
};

// Distributed full barrier: every block sets its own flag line, all blocks
// poll all nblk lines (thread t polls line t). Agent-scope load poll with a
// periodic RMW fallback guarantees progress (R6-validated coherence).
__device__ inline void dbar(unsigned* flg, int nblk) {
  __syncthreads();
  if (threadIdx.x == 0) {
    __threadfence();                       // release: this block's data
    atomicExch(&flg[blockIdx.x * FLAGSTRIDE], 1u);
  }
  if ((int)threadIdx.x < nblk) {
    int spin = 0;
    while (__hip_atomic_load(&flg[threadIdx.x * FLAGSTRIDE], __ATOMIC_ACQUIRE,
                             __HIP_MEMORY_SCOPE_AGENT) == 0u) {
      __builtin_amdgcn_s_sleep(2);
      if ((++spin & 255) == 0) {
        if (atomicAdd(&flg[threadIdx.x * FLAGSTRIDE], 0u) != 0u) break;
      }
    }
  }
  __syncthreads();
  if (threadIdx.x == 0) __threadfence();   // acquire: other blocks' data
  __syncthreads();
}

__global__ void __launch_bounds__(TPB, 4) sort_kernel(
    const float* __restrict__ scores, const float* __restrict__ mask,
    int N, int nT, unsigned* pflag, unsigned* ghist,
    unsigned* tileCnt, unsigned* keysA, unsigned* keysB, int* idxA, int* idxB) {
  __shared__ SortSM s;
  __shared__ unsigned base4[4][256];      // per-block copy of scanned bases
  const int tid = threadIdx.x;
  const int lane = tid & 63;
  const int wave = tid >> 6;              // 0..15

  // ---- P0: build keys + all 4 histograms in one read ----
  if (tid < 1024) s.h[tid] = 0;
  __syncthreads();
  {
    int i = blockIdx.x * TILE + tid;
    if (i < N) {
      float kf = scores[i] + logf(mask[i]);            // mask==1 -> +0 exact
      unsigned u = __float_as_uint(kf);
      u = (u & 0x80000000u) ? ~u : (u | 0x80000000u);
      u = ~u;                                          // descending order
      keysA[i] = u;
      atomicAdd(&s.h[(u & 255u)], 1u);
      atomicAdd(&s.h[256 + ((u >> 8) & 255u)], 1u);
      atomicAdd(&s.h[512 + ((u >> 16) & 255u)], 1u);
      atomicAdd(&s.h[768 + (u >> 24)], 1u);
    }
    __syncthreads();
    if (tid < 1024 && s.h[tid]) atomicAdd(&ghist[tid], s.h[tid]);
  }
  dbar(pflag + (size_t)4 * nT * FLAGSTRIDE, nT);

  // ---- digit-base exclusive scans: wave p (p<4) scans pass p via shfl ----
  if (wave < 4) {
    const int p = wave;
    unsigned v0 = ghist[p * 256 + 4 * lane + 0];
    unsigned v1 = ghist[p * 256 + 4 * lane + 1];
    unsigned v2 = ghist[p * 256 + 4 * lane + 2];
    unsigned v3 = ghist[p * 256 + 4 * lane + 3];
    unsigned sum = v0 + v1 + v2 + v3;
    unsigned x = sum;
    for (int off = 1; off < 64; off <<= 1) {
      unsigned y = __shfl_up(x, off, 64);
      if (lane >= off) x += y;
    }
    unsigned excl = x - sum;               // exclusive over 4-bin chunks
    base4[p][4 * lane + 0] = excl;
    base4[p][4 * lane + 1] = excl + v0;
    base4[p][4 * lane + 2] = excl + v0 + v1;
    base4[p][4 * lane + 3] = excl + v0 + v1 + v2;
  }
  __syncthreads();

  // ---- 4 fused rank/scatter radix passes (1 element per thread) ----
  for (int p = 0; p < 4; ++p) {
    const unsigned* srck = (p & 1) ? keysB : keysA;
    const int*      srci = (p & 1) ? idxB : idxA;     // p==0: payload = i
    unsigned*       dstk = (p & 1) ? keysA : keysB;
    int*            dsti = (p & 1) ? idxA : idxB;
    const int shift = 8 * p;
    unsigned* flg = pflag + (size_t)p * nT * FLAGSTRIDE;

    for (int j = tid; j < 16 * 256; j += TPB)
      (&s.wcnt[0][0])[j] = 0;
    __syncthreads();

    int i = blockIdx.x * TILE + tid;
    bool v = (i < N);
    unsigned key = v ? srck[i] : 0u;
    int pay = v ? ((p == 0) ? i : srci[i]) : 0;
    unsigned d = (key >> shift) & 255u;
    unsigned long long mm = __ballot(v);     // stable rank within wave
    #pragma unroll
    for (int b = 0; b < 8; ++b) {
      unsigned long long bb = __ballot((d >> b) & 1u);
      mm &= ((d >> b) & 1u) ? bb : ~bb;
    }
    unsigned rnk = (unsigned)__popcll(mm & ((1ull << lane) - 1ull));
    if (v && rnk == 0) s.wcnt[wave][d] = (unsigned)__popcll(mm);
    __syncthreads();
    if (tid < 256) {                       // one 16-way scan per digit
      unsigned run = 0;
      #pragma unroll
      for (int g = 0; g < 16; ++g) {
        unsigned c = s.wcnt[g][tid];
        s.wcnt[g][tid] = run;
        run += c;
      }
      tileCnt[blockIdx.x * 256 + tid] = run;
    }
    __syncthreads();                       // all tileCnt writes issued

    // ---- publish + decoupled lookback (block b needs only t<b) ----
    if (tid == 0) {
      __threadfence();                     // release: tileCnt visible
      atomicExch(&flg[blockIdx.x * FLAGSTRIDE], 1u);
    }
    if (tid < blockIdx.x) {                // one thread polls one predecessor
      while (atomicAdd(&flg[tid * FLAGSTRIDE], 0u) == 0u)
        __builtin_amdgcn_s_sleep(2);
    }
    __syncthreads();
    if (tid == 0) __threadfence();         // acquire: invalidate stale lines
    __syncthreads();

    // ---- 4-way chunked prefix accumulation: thread = (chunk,digit) ----
    {
      int digit = tid & 255;
      int chunk = tid >> 8;                // 0..3
      int b = blockIdx.x;
      int Q = (b + 3) >> 2;                // ceil(b/4)
      int t0 = chunk * Q;
      int t1 = t0 + Q; if (t1 > b) t1 = b;
      unsigned acc2 = 0;
      for (int t = t0; t < t1; ++t)
        acc2 += tileCnt[t * 256 + digit];
      s.part[chunk][digit] = acc2;
    }
    __syncthreads();
    if (tid < 256) {
      s.baseL[tid] = base4[p][tid] + s.part[0][tid] + s.part[1][tid]
                   + s.part[2][tid] + s.part[3][tid];
    }
    __syncthreads();
    if (v) {
      unsigned pos = s.baseL[d] + s.wcnt[wave][d] + rnk;
      dstk[pos] = key;
      dsti[pos] = pay;
    }
    if (p < 3) dbar(pflag + (size_t)(5 + p) * nT * FLAGSTRIDE, nT);
  }
  // final order in idxA (A->B->A->B->A)
}

// ===========================================================================
// Kernel B: batched-speculative greedy (1 block, 1024 threads) + epilogue.
// v10/v11/v14 (unchanged, best-measured ~110-123 us): 1 candidate/thread,
// wave-0 resolution with parallel fixpoint, tabP dirty-recheck. 16 waves.
// ===========================================================================
__device__ inline bool precheck30(const unsigned* tabP, int cc, int cs, int ce) {
  if (cc < 0) return false;
  int w = ce - cs;
  bool crossed = false;
  #pragma unroll
  for (int off = 0; off <= MAXW; ++off) {
    unsigned tv = tabP[cs + off];
    crossed |= ((off >= 1) & (off <= w) & ((tv & 0xFFFFu) > (unsigned)(ce + 1)))
             | ((off < w) & ((tv >> 16) < (unsigned)cs));
  }
  for (int off = MAXW + 1; off <= w; ++off) {   // generic fallback (unused)
    unsigned tv = tabP[cs + off];
    crossed |= ((tv & 0xFFFFu) > (unsigned)(ce + 1));
    if (off < w) crossed |= ((tv >> 16) < (unsigned)cs);
  }
  return !crossed;
}

__global__ void __launch_bounds__(TPB, 4) greedy_kernel(
    const int2* __restrict__ spans2, const int* __restrict__ spans,
    const float* __restrict__ scores, const int* __restrict__ order,
    const int* __restrict__ tnum_p, const int* __restrict__ keep_p,
    float* __restrict__ out, int N) {
  __shared__ unsigned tabP[MAXT + TPAD];  // hi16 = e2s(enc), lo16 = s2e+1
  __shared__ int2 tab[MAXT + TPAD];       // authoritative: .x=s2e, .y=e2s
  __shared__ unsigned long long acc[MAXK];
  __shared__ unsigned long long surv[BATCH];
  __shared__ unsigned long long Cmat[BATCH];   // in-group crossing rows
  __shared__ int wvs[16];                      // survivor count per wave
  __shared__ int gcnt;

  const int tid = threadIdx.x;
  const int lane = tid & 63;
  const int wave = tid >> 6;              // 0..15
  const int T  = tnum_p[0];
  const int k0 = keep_p[0];
  const int k  = (k0 < MAXK) ? k0 : MAXK;

  for (int t = tid; t < MAXT + TPAD; t += TPB) {
    tab[t] = make_int2(-1, INT_MAX);
    tabP[t] = 0xFFFF0000u;               // s2e+1 = 0, e2s_enc = 0xFFFF
  }
  if (tid == 0) gcnt = 0;
  __syncthreads();

  // Each thread owns candidate c0+tid of every round. ids prefetched 2
  // rounds ahead, spans 1 round ahead.
  int cc = -1, cs = 0, ce = 0, nn = -1;
  if (tid < N)         cc = order[tid];
  if (BATCH + tid < N) nn = order[BATCH + tid];
  if (cc >= 0) { int2 sp = spans2[cc]; cs = sp.x; ce = sp.y; }

  int cnt = 0;
  for (int c0 = 0; c0 < N && cnt < k; c0 += BATCH) {
    // ---- prefetch next-round span + next-next-round id ----
    int pc = nn, ps = 0, pe = 0;
    if (pc >= 0) { int2 sp = spans2[pc]; ps = sp.x; pe = sp.y; }
    int i2 = c0 + 2 * BATCH + tid;
    nn = (i2 < N) ? order[i2] : -1;

    // ---- parallel pre-check vs packed tables (monotone -> speculative) ----
    bool ok = precheck30(tabP, cc, cs, ce);
    unsigned long long bal = __ballot(ok);
    if (lane == 0) wvs[wave] = (int)__popcll(bal);
    __syncthreads();
    int ns = 0, wb = 0;
    #pragma unroll
    for (int w2 = 0; w2 < 16; ++w2) {
      if (w2 == wave) wb = ns;
      ns += wvs[w2];
    }

    if (ns > 0) {              // uniform branch: all threads agree on ns
      // ---- order-preserving survivor compression -> LDS ----
      if (ok) {
        int pos = wb + (int)__popcll(bal & ((1ull << lane) - 1ull));
        surv[pos] = ((unsigned long long)(unsigned)cs << 48)
                  | ((unsigned long long)(unsigned)ce << 32)
                  | (unsigned)cc;
      }
      __syncthreads();

      // ---- parallel in-group crossing-matrix precompute ----
      for (int v = tid; v < ns; v += TPB) {
        unsigned long long pk = surv[v];
        int gs = (int)(pk >> 48), ge = (int)((pk >> 32) & 0xFFFFu);
        int gbase = v & ~63;
        int m = ns - gbase; if (m > 64) m = 64;
        unsigned long long C = 0;
        for (int j = 0; j < m; ++j) {
          unsigned long long pj = surv[gbase + j];
          int sj = (int)(pj >> 48), ej = (int)((pj >> 32) & 0xFFFFu);
          bool cr = (gs < sj && sj <= ge && ej > ge) ||
                    (sj < gs && gs <= ej && ej < ge);
          C |= (unsigned long long)cr << j;
        }
        Cmat[v] = C;
      }
      __syncthreads();

      // ---- wave-0 resolution, 64 survivors at a time ----
      if (tid < 64) {
        bool dirty = false;    // any in-batch acceptance since pre-check?
        for (int g = 0; g < ns && cnt < k; g += 64) {
          int m = ns - g; if (m > 64) m = 64;
          bool act = lane < m;
          int gs = 0, ge = 0, gc = 0;
          unsigned long long C = 0;
          if (act) {
            unsigned long long pk = surv[g + lane];
            gs = (int)(pk >> 48);
            ge = (int)((pk >> 32) & 0xFFFFu);
            gc = (int)(unsigned)pk;
            C  = Cmat[g + lane];
          }
          bool pre = act;
          if (dirty) {         // re-check only when tables changed in-batch
            pre = act && precheck30(tabP, gc, gs, ge);
          }
          unsigned long long preB = __ballot(pre);
          if (preB == 0ull) continue;
          int np = (int)__popcll(preB);
          unsigned long long lower = (1ull << lane) - 1ull;
          unsigned long long accm;
          int cnt0g = cnt;
          if (np == 1) {                       // single-survivor fast path
            accm = preB;
            cnt += 1;
          } else {
            // ---- parallel fixpoint: resolve ready lanes each iteration ----
            unsigned long long Cl = C & lower;        // my earlier crossers
            unsigned long long resolvedB = ~preB;     // non-pre start rejected
            accm = 0ull;
            while (true) {
              bool meUn   = ((resolvedB >> lane) & 1ull) == 0ull;
              bool killed = (Cl & accm) != 0ull;
              bool ready  = (Cl & ~resolvedB) == 0ull;
              unsigned long long newacc = __ballot(meUn && ready && !killed);
              unsigned long long newrej = __ballot(meUn && killed);
              if (!(newacc | newrej)) break;
              accm |= newacc;
              resolvedB |= (newacc | newrej);
            }
            int nacc = (int)__popcll(accm);
            if (cnt + nacc > k) {              // k-cap: keep first (k-cnt)
              int room = k - cnt;
              bool a0 = ((accm >> lane) & 1ull) != 0ull;
              int ar = (int)__popcll(accm & lower);
              accm = __ballot(a0 && (ar < room));
              nacc = room;
            }
            cnt += nacc;
          }
          bool accme = ((accm >> lane) & 1ull) != 0ull;
          if (accme) {
            int rank = (int)__popcll(accm & lower);
            acc[cnt0g + rank] =
                ((unsigned long long)(unsigned)(gs * T + ge) << 32) | (unsigned)gc;
            atomicMax(&tab[gs].x, ge);
            atomicMin(&tab[ge].y, gs);
          }
          if (accme) {      // same-wave DS in-order: reads see all atomics
            int2 tv = tab[gs];
            tabP[gs] = ((unsigned)(tv.y > 65535 ? 65535 : tv.y) << 16)
                     | (unsigned)(tv.x + 1);
            int2 tv2 = tab[ge];
            tabP[ge] = ((unsigned)(tv2.y > 65535 ? 65535 : tv2.y) << 16)
                     | (unsigned)(tv2.x + 1);
          }
          if (accm) dirty = true;
        }
        if (lane == 0) gcnt = cnt;
      }
      __syncthreads();
      cnt = gcnt;
    }

    cc = pc; cs = ps; ce = pe;
  }

  // ---- bitonic ascending sort of acc[0..cnt) by (s*T+e, cand) ----
  int M = 2;
  while (M < cnt) M <<= 1;
  for (int j = tid; j < M; j += TPB)
    if (j >= cnt) acc[j] = ~0ull;
  __syncthreads();
  for (int kk = 2; kk <= M; kk <<= 1) {
    for (int jj = kk >> 1; jj > 0; jj >>= 1) {
      for (int i3 = tid; i3 < M; i3 += TPB) {
        int ixj = i3 ^ jj;
        if (ixj > i3) {
          unsigned long long a = acc[i3], b = acc[ixj];
          bool up = ((i3 & kk) == 0);
          if ((a > b) == up) { acc[i3] = b; acc[ixj] = a; }
        }
      }
      __syncthreads();
    }
  }

  // ---- epilogue: scores | idx | spans | valid, all f32 ----
  for (int j = tid; j < k0; j += TPB) {
    if (j < cnt) {
      int cand = (int)(acc[j] & 0xFFFFFFFFu);
      out[j]                  = scores[cand];
      out[k0 + j]             = (float)cand;
      out[2 * k0 + 2 * j]     = (float)spans[2 * cand];
      out[2 * k0 + 2 * j + 1] = (float)spans[2 * cand + 1];
      out[4 * k0 + j]         = 1.0f;
    } else {
      out[j]                  = 0.0f;
      out[k0 + j]             = 0.0f;
      out[2 * k0 + 2 * j]     = 0.0f;
      out[2 * k0 + 2 * j + 1] = 0.0f;
      out[4 * k0 + j]         = 0.0f;
    }
  }
}

extern "C" void kernel_launch(void* const* d_in, const int* in_sizes, int n_in,
                              void* d_out, int out_size, void* d_ws, size_t ws_size,
                              hipStream_t stream) {
  const int*   spans  = (const int*)d_in[0];
  const float* scores = (const float*)d_in[1];
  const float* mask   = (const float*)d_in[2];
  const int*   tnum   = (const int*)d_in[3];
  const int*   keep   = (const int*)d_in[4];
  const int N = in_sizes[1];
  const int nT = (N + TILE - 1) / TILE;   // 60 for N=61440

  // ws: pflag[8*nT*FS] | ghist[1024] | tileCnt[nT*256] | keysA/B | idxA/B
  unsigned* pflag   = (unsigned*)d_ws;
  unsigned* ghist   = pflag + (size_t)8 * nT * FLAGSTRIDE;
  unsigned* tileCnt = ghist + 1024;
  unsigned* keysA   = tileCnt + (size_t)nT * 256;
  unsigned* keysB   = keysA + N;
  int*      idxA    = (int*)(keysB + N);
  int*      idxB    = idxA + N;
  float*    out     = (float*)d_out;

  hipMemsetAsync(pflag, 0,
                 ((size_t)8 * nT * FLAGSTRIDE + 1024) * sizeof(unsigned),
                 stream);

  sort_kernel<<<nT, TPB, 0, stream>>>(scores, mask, N, nT, pflag, ghist,
                                      tileCnt, keysA, keysB, idxA, idxB);
  greedy_kernel<<<1, TPB, 0, stream>>>((const int2*)spans, spans, scores,
                                       idxA, tnum, keep, out, N);
}

// Round 16
// 219.005 us; speedup vs baseline: 1.1583x; 1.0395x over previous
//
#include <hip/hip_runtime.h>
#include <math.h>
#include <limits.h>

#define TPB   1024          // 16 waves/block = 4 waves/SIMD (latency hiding)
#define TILE  1024          // sort: 1 element per thread
#define MAXT  2048
#define TPAD  64            // pad so unconditional reads past e stay in-bounds
#define MAXK  1024
#define MAXW  29            // max span width in this problem (W=30 -> w<=29)
#define BATCH 960           // greedy candidates per round (waves 1-15, 1/thr)
#define FLAGSTRIDE 16       // words per flag (64B line each)

// ===========================================================================
// Kernel A: fused key-build + 4-pass LSD radix argsort (60 blocks x 1024 thr)
// (v15 sort, unchanged: distributed-flag full barriers + decoupled lookback
//  + 4-way chunked baseL accumulation.)
// ===========================================================================
struct SortSM {
  union {
    unsigned h[4 * 256];                  // P0: 4 pass histograms
    unsigned wcnt[16][256];               // [wave][digit], scanned in place
  };
  unsigned baseL[256];
  unsigned part[4][256];                  // chunked tileCnt partial sums
};

__device__ inline void dbar(unsigned* flg, int nblk) {
  __syncthreads();
  if (threadIdx.x == 0) {
    __threadfence();                       // release: this block's data
    atomicExch(&flg[blockIdx.x * FLAGSTRIDE], 1u);
  }
  if ((int)threadIdx.x < nblk) {
    int spin = 0;
    while (__hip_atomic_load(&flg[threadIdx.x * FLAGSTRIDE], __ATOMIC_ACQUIRE,
                             __HIP_MEMORY_SCOPE_AGENT) == 0u) {
      __builtin_amdgcn_s_sleep(2);
      if ((++spin & 255) == 0) {
        if (atomicAdd(&flg[threadIdx.x * FLAGSTRIDE], 0u) != 0u) break;
      }
    }
  }
  __syncthreads();
  if (threadIdx.x == 0) __threadfence();   // acquire: other blocks' data
  __syncthreads();
}

__global__ void __launch_bounds__(TPB, 4) sort_kernel(
    const float* __restrict__ scores, const float* __restrict__ mask,
    int N, int nT, unsigned* pflag, unsigned* ghist,
    unsigned* tileCnt, unsigned* keysA, unsigned* keysB, int* idxA, int* idxB) {
  __shared__ SortSM s;
  __shared__ unsigned base4[4][256];      // per-block copy of scanned bases
  const int tid = threadIdx.x;
  const int lane = tid & 63;
  const int wave = tid >> 6;              // 0..15

  // ---- P0: build keys + all 4 histograms in one read ----
  if (tid < 1024) s.h[tid] = 0;
  __syncthreads();
  {
    int i = blockIdx.x * TILE + tid;
    if (i < N) {
      float kf = scores[i] + logf(mask[i]);            // mask==1 -> +0 exact
      unsigned u = __float_as_uint(kf);
      u = (u & 0x80000000u) ? ~u : (u | 0x80000000u);
      u = ~u;                                          // descending order
      keysA[i] = u;
      atomicAdd(&s.h[(u & 255u)], 1u);
      atomicAdd(&s.h[256 + ((u >> 8) & 255u)], 1u);
      atomicAdd(&s.h[512 + ((u >> 16) & 255u)], 1u);
      atomicAdd(&s.h[768 + (u >> 24)], 1u);
    }
    __syncthreads();
    if (tid < 1024 && s.h[tid]) atomicAdd(&ghist[tid], s.h[tid]);
  }
  dbar(pflag + (size_t)4 * nT * FLAGSTRIDE, nT);

  // ---- digit-base exclusive scans: wave p (p<4) scans pass p via shfl ----
  if (wave < 4) {
    const int p = wave;
    unsigned v0 = ghist[p * 256 + 4 * lane + 0];
    unsigned v1 = ghist[p * 256 + 4 * lane + 1];
    unsigned v2 = ghist[p * 256 + 4 * lane + 2];
    unsigned v3 = ghist[p * 256 + 4 * lane + 3];
    unsigned sum = v0 + v1 + v2 + v3;
    unsigned x = sum;
    for (int off = 1; off < 64; off <<= 1) {
      unsigned y = __shfl_up(x, off, 64);
      if (lane >= off) x += y;
    }
    unsigned excl = x - sum;               // exclusive over 4-bin chunks
    base4[p][4 * lane + 0] = excl;
    base4[p][4 * lane + 1] = excl + v0;
    base4[p][4 * lane + 2] = excl + v0 + v1;
    base4[p][4 * lane + 3] = excl + v0 + v1 + v2;
  }
  __syncthreads();

  // ---- 4 fused rank/scatter radix passes (1 element per thread) ----
  for (int p = 0; p < 4; ++p) {
    const unsigned* srck = (p & 1) ? keysB : keysA;
    const int*      srci = (p & 1) ? idxB : idxA;     // p==0: payload = i
    unsigned*       dstk = (p & 1) ? keysA : keysB;
    int*            dsti = (p & 1) ? idxA : idxB;
    const int shift = 8 * p;
    unsigned* flg = pflag + (size_t)p * nT * FLAGSTRIDE;

    for (int j = tid; j < 16 * 256; j += TPB)
      (&s.wcnt[0][0])[j] = 0;
    __syncthreads();

    int i = blockIdx.x * TILE + tid;
    bool v = (i < N);
    unsigned key = v ? srck[i] : 0u;
    int pay = v ? ((p == 0) ? i : srci[i]) : 0;
    unsigned d = (key >> shift) & 255u;
    unsigned long long mm = __ballot(v);     // stable rank within wave
    #pragma unroll
    for (int b = 0; b < 8; ++b) {
      unsigned long long bb = __ballot((d >> b) & 1u);
      mm &= ((d >> b) & 1u) ? bb : ~bb;
    }
    unsigned rnk = (unsigned)__popcll(mm & ((1ull << lane) - 1ull));
    if (v && rnk == 0) s.wcnt[wave][d] = (unsigned)__popcll(mm);
    __syncthreads();
    if (tid < 256) {                       // one 16-way scan per digit
      unsigned run = 0;
      #pragma unroll
      for (int g = 0; g < 16; ++g) {
        unsigned c = s.wcnt[g][tid];
        s.wcnt[g][tid] = run;
        run += c;
      }
      tileCnt[blockIdx.x * 256 + tid] = run;
    }
    __syncthreads();                       // all tileCnt writes issued

    // ---- publish + decoupled lookback (block b needs only t<b) ----
    if (tid == 0) {
      __threadfence();                     // release: tileCnt visible
      atomicExch(&flg[blockIdx.x * FLAGSTRIDE], 1u);
    }
    if (tid < blockIdx.x) {                // one thread polls one predecessor
      while (atomicAdd(&flg[tid * FLAGSTRIDE], 0u) == 0u)
        __builtin_amdgcn_s_sleep(2);
    }
    __syncthreads();
    if (tid == 0) __threadfence();         // acquire: invalidate stale lines
    __syncthreads();

    // ---- 4-way chunked prefix accumulation: thread = (chunk,digit) ----
    {
      int digit = tid & 255;
      int chunk = tid >> 8;                // 0..3
      int b = blockIdx.x;
      int Q = (b + 3) >> 2;                // ceil(b/4)
      int t0 = chunk * Q;
      int t1 = t0 + Q; if (t1 > b) t1 = b;
      unsigned acc2 = 0;
      for (int t = t0; t < t1; ++t)
        acc2 += tileCnt[t * 256 + digit];
      s.part[chunk][digit] = acc2;
    }
    __syncthreads();
    if (tid < 256) {
      s.baseL[tid] = base4[p][tid] + s.part[0][tid] + s.part[1][tid]
                   + s.part[2][tid] + s.part[3][tid];
    }
    __syncthreads();
    if (v) {
      unsigned pos = s.baseL[d] + s.wcnt[wave][d] + rnk;
      dstk[pos] = key;
      dsti[pos] = pay;
    }
    if (p < 3) dbar(pflag + (size_t)(5 + p) * nT * FLAGSTRIDE, nT);
  }
  // final order in idxA (A->B->A->B->A)
}

// ===========================================================================
// Kernel B: PIPELINED batched-speculative greedy (1 block, 1024 threads).
// v16: producer-consumer within the block — wave 0 resolves batch t (buffer
//      A) while waves 1-15 pre-check/compact/Cmat batch t+1 (buffer B,
//      BATCH=960, 1 cand/thread). Waves 1-15 coordinate via 2 LDS soft
//      barriers; one full __syncthreads per round joins + swaps buffers.
//      Pre-check is now stale-by-design -> resolver recheck UNCONDITIONAL
//      (replaces the old 'dirty' flag; stale survivors fail recheck, are
//      never in preB, and cannot kill others in the fixpoint).
// ===========================================================================
__device__ inline bool precheck30(const unsigned* tabP, int cc, int cs, int ce) {
  if (cc < 0) return false;
  int w = ce - cs;
  bool crossed = false;
  #pragma unroll
  for (int off = 0; off <= MAXW; ++off) {
    unsigned tv = tabP[cs + off];
    crossed |= ((off >= 1) & (off <= w) & ((tv & 0xFFFFu) > (unsigned)(ce + 1)))
             | ((off < w) & ((tv >> 16) < (unsigned)cs));
  }
  for (int off = MAXW + 1; off <= w; ++off) {   // generic fallback (unused)
    unsigned tv = tabP[cs + off];
    crossed |= ((tv & 0xFFFFu) > (unsigned)(ce + 1));
    if (off < w) crossed |= ((tv >> 16) < (unsigned)cs);
  }
  return !crossed;
}

// Soft barrier among waves 1..15 (wave 0 never calls): monotonic counter.
__device__ inline void softbar(unsigned* sbar, unsigned target) {
  if ((threadIdx.x & 63) == 0)
    __hip_atomic_fetch_add(sbar, 1u, __ATOMIC_ACQ_REL,
                           __HIP_MEMORY_SCOPE_WORKGROUP);
  while (__hip_atomic_load(sbar, __ATOMIC_ACQUIRE,
                           __HIP_MEMORY_SCOPE_WORKGROUP) < target)
    __builtin_amdgcn_s_sleep(1);
}

__global__ void __launch_bounds__(TPB, 4) greedy_kernel(
    const int2* __restrict__ spans2, const int* __restrict__ spans,
    const float* __restrict__ scores, const int* __restrict__ order,
    const int* __restrict__ tnum_p, const int* __restrict__ keep_p,
    float* __restrict__ out, int N) {
  __shared__ unsigned tabP[MAXT + TPAD];  // hi16 = e2s(enc), lo16 = s2e+1
  __shared__ int2 tab[MAXT + TPAD];       // authoritative: .x=s2e, .y=e2s
  __shared__ unsigned long long acc[MAXK];
  __shared__ unsigned long long surv0[BATCH], surv1[BATCH];
  __shared__ unsigned long long cmat0[BATCH], cmat1[BATCH];
  __shared__ int wvs[16];                 // survivor count per wave (1..15)
  __shared__ int ns_s[2];                 // survivor count per buffer
  __shared__ unsigned sbar;               // soft-barrier counter (monotonic)
  __shared__ int gcnt;

  const int tid = threadIdx.x;
  const int lane = tid & 63;
  const int wave = tid >> 6;              // 0..15
  const int T  = tnum_p[0];
  const int k0 = keep_p[0];
  const int k  = (k0 < MAXK) ? k0 : MAXK;

  for (int t = tid; t < MAXT + TPAD; t += TPB) {
    tab[t] = make_int2(-1, INT_MAX);
    tabP[t] = 0xFFFF0000u;               // s2e+1 = 0, e2s_enc = 0xFFFF
  }
  if (tid == 0) { gcnt = 0; ns_s[0] = 0; ns_s[1] = 0; sbar = 0u; }
  if (tid < 16) wvs[tid] = 0;
  __syncthreads();

  // Waves 1-15 own candidate q = tid-64 of each batch; 2-deep id prefetch.
  int cc = -1, cs = 0, ce = 0, nn = -1;
  if (tid >= 64) {
    int q = tid - 64;
    if (q < N)          cc = order[q];
    if (BATCH + q < N)  nn = order[BATCH + q];
    if (cc >= 0) { int2 sp = spans2[cc]; cs = sp.x; ce = sp.y; }
  }

  unsigned long long* sA = surv0; unsigned long long* cA = cmat0;
  unsigned long long* sB = surv1; unsigned long long* cB = cmat1;
  int bufA = 0;
  int cnt = 0;
  int it = 0;
  // Iteration it: wave 0 resolves buffer A (prepped last iter; empty at it=0)
  // while waves 1-15 prep batch [c0, c0+BATCH) into buffer B.
  for (long c0 = 0; c0 < (long)N + BATCH && cnt < k; c0 += BATCH, ++it) {
    if (wave == 0) {
      // ================= RESOLVE buffer A (64 lanes) =================
      int nsA = ns_s[bufA];
      for (int g = 0; g < nsA && cnt < k; g += 64) {
        int m = nsA - g; if (m > 64) m = 64;
        bool act = lane < m;
        int gs = 0, ge = 0, gc = 0;
        unsigned long long C = 0;
        if (act) {
          unsigned long long pk = sA[g + lane];
          gs = (int)(pk >> 48);
          ge = (int)((pk >> 32) & 0xFFFFu);
          gc = (int)(unsigned)pk;
          C  = cA[g + lane];
        }
        // UNCONDITIONAL recheck vs authoritative tables (pre-check is stale)
        bool pre = act && precheck30(tabP, gc, gs, ge);
        unsigned long long preB = __ballot(pre);
        if (preB == 0ull) continue;
        int np = (int)__popcll(preB);
        unsigned long long lower = (1ull << lane) - 1ull;
        unsigned long long accm;
        int cnt0g = cnt;
        if (np == 1) {                       // single-survivor fast path
          accm = preB;
          cnt += 1;
        } else {
          // parallel fixpoint: resolve ready lanes each iteration
          unsigned long long Cl = C & lower;        // my earlier crossers
          unsigned long long resolvedB = ~preB;     // non-pre start rejected
          accm = 0ull;
          while (true) {
            bool meUn   = ((resolvedB >> lane) & 1ull) == 0ull;
            bool killed = (Cl & accm) != 0ull;
            bool ready  = (Cl & ~resolvedB) == 0ull;
            unsigned long long newacc = __ballot(meUn && ready && !killed);
            unsigned long long newrej = __ballot(meUn && killed);
            if (!(newacc | newrej)) break;
            accm |= newacc;
            resolvedB |= (newacc | newrej);
          }
          int nacc = (int)__popcll(accm);
          if (cnt + nacc > k) {              // k-cap: keep first (k-cnt)
            int room = k - cnt;
            bool a0 = ((accm >> lane) & 1ull) != 0ull;
            int ar = (int)__popcll(accm & lower);
            accm = __ballot(a0 && (ar < room));
            nacc = room;
          }
          cnt += nacc;
        }
        bool accme = ((accm >> lane) & 1ull) != 0ull;
        if (accme) {
          int rank = (int)__popcll(accm & lower);
          acc[cnt0g + rank] =
              ((unsigned long long)(unsigned)(gs * T + ge) << 32) | (unsigned)gc;
          atomicMax(&tab[gs].x, ge);
          atomicMin(&tab[ge].y, gs);
        }
        if (accme) {      // same-wave DS in-order: reads see all atomics
          int2 tv = tab[gs];
          tabP[gs] = ((unsigned)(tv.y > 65535 ? 65535 : tv.y) << 16)
                   | (unsigned)(tv.x + 1);
          int2 tv2 = tab[ge];
          tabP[ge] = ((unsigned)(tv2.y > 65535 ? 65535 : tv2.y) << 16)
                   | (unsigned)(tv2.x + 1);
        }
      }
      if (lane == 0) gcnt = cnt;
    } else {
      // ============ PREP batch [c0, c0+BATCH) into buffer B ============
      int q = tid - 64;
      int pc = nn, ps = 0, pe = 0;
      if (pc >= 0) { int2 sp = spans2[pc]; ps = sp.x; pe = sp.y; }
      long i2 = c0 + 2 * (long)BATCH + q;
      nn = (i2 < N) ? order[i2] : -1;

      // speculative pre-check vs (possibly mid-update) tabP
      bool ok = precheck30(tabP, cc, cs, ce);
      unsigned long long bal = __ballot(ok);
      if (lane == 0) wvs[wave] = (int)__popcll(bal);
      softbar(&sbar, 15u * (2u * (unsigned)it + 1u));
      int ns = 0, wb = 0;
      #pragma unroll
      for (int w2 = 1; w2 < 16; ++w2) {
        if (w2 == wave) wb = ns;
        ns += wvs[w2];
      }
      if (ok) {
        int pos = wb + (int)__popcll(bal & ((1ull << lane) - 1ull));
        sB[pos] = ((unsigned long long)(unsigned)cs << 48)
                | ((unsigned long long)(unsigned)ce << 32)
                | (unsigned)cc;
      }
      if (wave == 1 && lane == 0) ns_s[bufA ^ 1] = ns;
      softbar(&sbar, 15u * (2u * (unsigned)it + 2u));
      // Cmat for buffer B (960 threads, stride BATCH)
      for (int v = q; v < ns; v += BATCH) {
        unsigned long long pk = sB[v];
        int gs = (int)(pk >> 48), ge = (int)((pk >> 32) & 0xFFFFu);
        int gbase = v & ~63;
        int m = ns - gbase; if (m > 64) m = 64;
        unsigned long long C = 0;
        for (int j = 0; j < m; ++j) {
          unsigned long long pj = sB[gbase + j];
          int sj = (int)(pj >> 48), ej = (int)((pj >> 32) & 0xFFFFu);
          bool cr = (gs < sj && sj <= ge && ej > ge) ||
                    (sj < gs && gs <= ej && ej < ge);
          C |= (unsigned long long)cr << j;
        }
        cB[v] = C;
      }
      cc = pc; cs = ps; ce = pe;
    }
    __syncthreads();                       // join: A resolved, B prepped
    cnt = gcnt;
    { unsigned long long* t = sA; sA = sB; sB = t;
      t = cA; cA = cB; cB = t; }
    bufA ^= 1;
  }

  // ---- bitonic ascending sort of acc[0..cnt) by (s*T+e, cand) ----
  int M = 2;
  while (M < cnt) M <<= 1;
  for (int j = tid; j < M; j += TPB)
    if (j >= cnt) acc[j] = ~0ull;
  __syncthreads();
  for (int kk = 2; kk <= M; kk <<= 1) {
    for (int jj = kk >> 1; jj > 0; jj >>= 1) {
      for (int i3 = tid; i3 < M; i3 += TPB) {
        int ixj = i3 ^ jj;
        if (ixj > i3) {
          unsigned long long a = acc[i3], b = acc[ixj];
          bool up = ((i3 & kk) == 0);
          if ((a > b) == up) { acc[i3] = b; acc[ixj] = a; }
        }
      }
      __syncthreads();
    }
  }

  // ---- epilogue: scores | idx | spans | valid, all f32 ----
  for (int j = tid; j < k0; j += TPB) {
    if (j < cnt) {
      int cand = (int)(acc[j] & 0xFFFFFFFFu);
      out[j]                  = scores[cand];
      out[k0 + j]             = (float)cand;
      out[2 * k0 + 2 * j]     = (float)spans[2 * cand];
      out[2 * k0 + 2 * j + 1] = (float)spans[2 * cand + 1];
      out[4 * k0 + j]         = 1.0f;
    } else {
      out[j]                  = 0.0f;
      out[k0 + j]             = 0.0f;
      out[2 * k0 + 2 * j]     = 0.0f;
      out[2 * k0 + 2 * j + 1] = 0.0f;
      out[4 * k0 + j]         = 0.0f;
    }
  }
}

extern "C" void kernel_launch(void* const* d_in, const int* in_sizes, int n_in,
                              void* d_out, int out_size, void* d_ws, size_t ws_size,
                              hipStream_t stream) {
  const int*   spans  = (const int*)d_in[0];
  const float* scores = (const float*)d_in[1];
  const float* mask   = (const float*)d_in[2];
  const int*   tnum   = (const int*)d_in[3];
  const int*   keep   = (const int*)d_in[4];
  const int N = in_sizes[1];
  const int nT = (N + TILE - 1) / TILE;   // 60 for N=61440

  // ws: pflag[8*nT*FS] | ghist[1024] | tileCnt[nT*256] | keysA/B | idxA/B
  unsigned* pflag   = (unsigned*)d_ws;
  unsigned* ghist   = pflag + (size_t)8 * nT * FLAGSTRIDE;
  unsigned* tileCnt = ghist + 1024;
  unsigned* keysA   = tileCnt + (size_t)nT * 256;
  unsigned* keysB   = keysA + N;
  int*      idxA    = (int*)(keysB + N);
  int*      idxB    = idxA + N;
  float*    out     = (float*)d_out;

  hipMemsetAsync(pflag, 0,
                 ((size_t)8 * nT * FLAGSTRIDE + 1024) * sizeof(unsigned),
                 stream);

  sort_kernel<<<nT, TPB, 0, stream>>>(scores, mask, N, nT, pflag, ghist,
                                      tileCnt, keysA, keysB, idxA, idxB);
  greedy_kernel<<<1, TPB, 0, stream>>>((const int2*)spans, spans, scores,
                                       idxA, tnum, keep, out, N);
}